// Round 2
// baseline (591.945 us; speedup 1.0000x reference)
//
#include <hip/hip_runtime.h>
#include <math.h>

#define DDIM 256
#define HDIM 64
#define NTOK 1024
#define BDIM 256

// ---------------- k_pre: c1[h] = sum_d gamma[d]*W1[d,h]; c2[h] = sum_d beta[d]*W1[d,h] + b1[h]
__global__ void k_pre(const float* __restrict__ gamma, const float* __restrict__ beta,
                      const float* __restrict__ W1, const float* __restrict__ b1,
                      float* __restrict__ c12) {
    int h = threadIdx.x;
    if (h < HDIM) {
        float s1 = 0.f, s2 = 0.f;
        for (int d = 0; d < DDIM; ++d) {
            float w = W1[d * HDIM + h];
            s1 = fmaf(gamma[d], w, s1);
            s2 = fmaf(beta[d],  w, s2);
        }
        c12[h]        = s1;
        c12[HDIM + h] = s2 + b1[h];
    }
}

// ---------------- k_logits: 2 threads per token, 32 h each.
// threads [0,128) = h-half 0 (waves 0,1), threads [128,256) = h-half 1 (waves 2,3):
// half is wave-uniform, so W1/c12/W2 accesses stay on the scalar path.
// acc[32] halves VGPR pressure vs acc[64]; grid doubles to 2048 blocks -> 32 waves/CU.
__global__ __launch_bounds__(256) void k_logits(
    const float* __restrict__ x, const float* __restrict__ gamma,
    const float* __restrict__ W1, const float* __restrict__ W2,
    const float* __restrict__ c12, float* __restrict__ logits) {
    __shared__ float plog[128];
    int half = threadIdx.x >> 7;       // wave-uniform
    int tl   = threadIdx.x & 127;
    size_t t = (size_t)blockIdx.x * 128 + tl;
    const float4* row = reinterpret_cast<const float4*>(x + t * DDIM);
    const float* Wh   = W1 + half * 32;   // this half's 32 columns

    float acc[32];
    #pragma unroll
    for (int h = 0; h < 32; ++h) acc[h] = 0.f;
    float sum = 0.f, sq = 0.f;

    for (int i = 0; i < DDIM / 4; ++i) {
        float4 v = row[i];
        sum += (v.x + v.y) + (v.z + v.w);
        sq = fmaf(v.x, v.x, sq); sq = fmaf(v.y, v.y, sq);
        sq = fmaf(v.z, v.z, sq); sq = fmaf(v.w, v.w, sq);
        float xs[4] = {v.x, v.y, v.z, v.w};
        #pragma unroll
        for (int j = 0; j < 4; ++j) {
            int d = i * 4 + j;
            float xg = xs[j] * gamma[d];          // wave-uniform -> s_load
            #pragma unroll
            for (int h = 0; h < 32; ++h)          // 32 floats/d -> SGPR room to prefetch
                acc[h] = fmaf(xg, Wh[d * HDIM + h], acc[h]);
        }
    }

    float mu   = sum * (1.f / DDIM);
    float var  = fmaf(-mu, mu, sq * (1.f / DDIM));
    float sinv = rsqrtf(var + 1e-5f);

    float pl = 0.f;
    #pragma unroll
    for (int h = 0; h < 32; ++h) {
        int hg = half * 32 + h;                   // wave-uniform
        float pre = fmaf(sinv, fmaf(-mu, c12[hg], acc[h]), c12[HDIM + hg]);
        float g   = 0.5f * pre * (1.f + erff(pre * 0.70710678118654752f));
        pl = fmaf(g, W2[hg], pl);
    }

    if (half) plog[tl] = pl;
    __syncthreads();
    if (!half) logits[t] = pl + plog[tl];
}

// ---------------- k_softmax: one block per b, in-place logits -> weights (softmax over N).
// b2 omitted: softmax is shift-invariant.
__global__ __launch_bounds__(256) void k_softmax(float* __restrict__ wts) {
    __shared__ float smax[4], ssum[4];
    int b = blockIdx.x;
    float* row = wts + (size_t)b * NTOK;
    int w = threadIdx.x >> 6, lane = threadIdx.x & 63;

    float v[4];
    float m = -1e30f;
    #pragma unroll
    for (int k = 0; k < 4; ++k) { v[k] = row[threadIdx.x + 256 * k]; m = fmaxf(m, v[k]); }
    #pragma unroll
    for (int off = 32; off; off >>= 1) m = fmaxf(m, __shfl_xor(m, off));
    if (lane == 0) smax[w] = m;
    __syncthreads();
    m = fmaxf(fmaxf(smax[0], smax[1]), fmaxf(smax[2], smax[3]));

    float s = 0.f;
    #pragma unroll
    for (int k = 0; k < 4; ++k) { v[k] = __expf(v[k] - m); s += v[k]; }
    #pragma unroll
    for (int off = 32; off; off >>= 1) s += __shfl_xor(s, off);
    if (lane == 0) ssum[w] = s;
    __syncthreads();
    s = (ssum[0] + ssum[1]) + (ssum[2] + ssum[3]);
    float inv = 1.f / s;
    #pragma unroll
    for (int k = 0; k < 4; ++k) row[threadIdx.x + 256 * k] = v[k] * inv;
}

// ---------------- k_partial: summary partials. blockIdx.x = n-split, blockIdx.y = b.
// thread = d (perfectly coalesced x reads), w[b][n] wave-uniform -> s_load.
__global__ __launch_bounds__(256) void k_partial(const float* __restrict__ x,
                                                 const float* __restrict__ wts,
                                                 float* __restrict__ part, int rows) {
    int b = blockIdx.y, s = blockIdx.x, d = threadIdx.x;
    int n0 = s * rows;
    const float* w  = wts + (size_t)b * NTOK + n0;
    const float* xp = x + ((size_t)b * NTOK + n0) * DDIM + d;

    float a0 = 0.f, a1 = 0.f, a2 = 0.f, a3 = 0.f, a4 = 0.f, a5 = 0.f, a6 = 0.f, a7 = 0.f;
    for (int n = 0; n < rows; n += 8) {
        a0 = fmaf(w[n + 0], xp[(size_t)(n + 0) * DDIM], a0);
        a1 = fmaf(w[n + 1], xp[(size_t)(n + 1) * DDIM], a1);
        a2 = fmaf(w[n + 2], xp[(size_t)(n + 2) * DDIM], a2);
        a3 = fmaf(w[n + 3], xp[(size_t)(n + 3) * DDIM], a3);
        a4 = fmaf(w[n + 4], xp[(size_t)(n + 4) * DDIM], a4);
        a5 = fmaf(w[n + 5], xp[(size_t)(n + 5) * DDIM], a5);
        a6 = fmaf(w[n + 6], xp[(size_t)(n + 6) * DDIM], a6);
        a7 = fmaf(w[n + 7], xp[(size_t)(n + 7) * DDIM], a7);
    }
    float acc = ((a0 + a1) + (a2 + a3)) + ((a4 + a5) + (a6 + a7));
    part[((size_t)(b * gridDim.x + s)) * DDIM + d] = acc;
}

// ---------------- k_reduce: summary[b,d] = sum_s part[b,s,d]
__global__ __launch_bounds__(256) void k_reduce(const float* __restrict__ part,
                                                float* __restrict__ out, int nsplit) {
    int i = blockIdx.x * 256 + threadIdx.x;   // i over B*D
    int b = i >> 8, d = i & 255;
    float s = 0.f;
    for (int k = 0; k < nsplit; ++k) s += part[((size_t)(b * nsplit + k)) * DDIM + d];
    out[i] = s;
}

extern "C" void kernel_launch(void* const* d_in, const int* in_sizes, int n_in,
                              void* d_out, int out_size, void* d_ws, size_t ws_size,
                              hipStream_t stream) {
    const float* x     = (const float*)d_in[0];
    const float* gamma = (const float*)d_in[1];
    const float* beta  = (const float*)d_in[2];
    const float* W1    = (const float*)d_in[3];
    const float* b1    = (const float*)d_in[4];
    const float* W2    = (const float*)d_in[5];
    // d_in[6] = b2: softmax-invariant, unused.

    float* out     = (float*)d_out;
    float* summary = out;                       // B*D
    float* wts     = out + (size_t)BDIM * DDIM; // B*N (logits staged here, then weights)

    float* c12  = (float*)d_ws;                 // 128 floats
    float* part = c12 + 128;                    // up to 8*B*D floats

    const int NSPLIT = 8;
    size_t need = (128 + (size_t)NSPLIT * BDIM * DDIM) * sizeof(float);
    bool split = (ws_size >= need);

    hipLaunchKernelGGL(k_pre, dim3(1), dim3(64), 0, stream, gamma, beta, W1, b1, c12);
    hipLaunchKernelGGL(k_logits, dim3(BDIM * NTOK / 128), dim3(256), 0, stream,
                       x, gamma, W1, W2, c12, wts);
    hipLaunchKernelGGL(k_softmax, dim3(BDIM), dim3(256), 0, stream, wts);
    if (split) {
        hipLaunchKernelGGL(k_partial, dim3(NSPLIT, BDIM), dim3(256), 0, stream,
                           x, wts, part, NTOK / NSPLIT);
        hipLaunchKernelGGL(k_reduce, dim3(BDIM * DDIM / 256), dim3(256), 0, stream,
                           part, summary, NSPLIT);
    } else {
        hipLaunchKernelGGL(k_partial, dim3(1, BDIM), dim3(256), 0, stream,
                           x, wts, summary, NTOK);
    }
}

// Round 3
// 204.180 us; speedup vs baseline: 2.8991x; 2.8991x over previous
//
#include <hip/hip_runtime.h>
#include <math.h>

#define DDIM 256
#define HDIM 64
#define NTOK 1024
#define BDIM 256

// ---------------- k_pre: c1[h] = sum_d gamma[d]*W1[d,h]; c2[h] = sum_d beta[d]*W1[d,h] + b1[h]
__global__ void k_pre(const float* __restrict__ gamma, const float* __restrict__ beta,
                      const float* __restrict__ W1, const float* __restrict__ b1,
                      float* __restrict__ c12) {
    int h = threadIdx.x;
    if (h < HDIM) {
        float s1 = 0.f, s2 = 0.f;
        for (int d = 0; d < DDIM; ++d) {
            float w = W1[d * HDIM + h];
            s1 = fmaf(gamma[d], w, s1);
            s2 = fmaf(beta[d],  w, s2);
        }
        c12[h]        = s1;
        c12[HDIM + h] = s2 + b1[h];
    }
}

// ---------------- k_logits: 2 threads per token, 32 h each.
// half is wave-uniform (waves 0,1 -> 0; waves 2,3 -> 1) and is FORCED onto the
// scalar path via readfirstlane so W1/c12/W2 stay s_load operands (R1 lost this:
// SGPR_Count fell to 32 and every W1 element became a per-lane global_load).
__global__ __launch_bounds__(256) void k_logits(
    const float* __restrict__ x, const float* __restrict__ gamma,
    const float* __restrict__ W1, const float* __restrict__ W2,
    const float* __restrict__ c12, float* __restrict__ logits) {
    __shared__ float plog[128];
    int half = __builtin_amdgcn_readfirstlane(threadIdx.x >> 7);   // SGPR, exact per-wave
    int tl   = threadIdx.x & 127;
    size_t t = (size_t)blockIdx.x * 128 + tl;
    const float4* row = reinterpret_cast<const float4*>(x + t * DDIM);
    const float* Wh   = W1 + half * 32;   // scalar pointer -> s_load path

    float acc[32];
    #pragma unroll
    for (int h = 0; h < 32; ++h) acc[h] = 0.f;
    float sum = 0.f, sq = 0.f;

    for (int i = 0; i < DDIM / 4; ++i) {
        float4 v = row[i];
        sum += (v.x + v.y) + (v.z + v.w);
        sq = fmaf(v.x, v.x, sq); sq = fmaf(v.y, v.y, sq);
        sq = fmaf(v.z, v.z, sq); sq = fmaf(v.w, v.w, sq);
        float xs[4] = {v.x, v.y, v.z, v.w};
        #pragma unroll
        for (int j = 0; j < 4; ++j) {
            int d = i * 4 + j;
            float xg = xs[j] * gamma[d];          // wave-uniform -> s_load
            #pragma unroll
            for (int h = 0; h < 32; ++h)          // 32 floats/d -> SGPR room to prefetch
                acc[h] = fmaf(xg, Wh[d * HDIM + h], acc[h]);
        }
    }

    float mu   = sum * (1.f / DDIM);
    float var  = fmaf(-mu, mu, sq * (1.f / DDIM));
    float sinv = rsqrtf(var + 1e-5f);

    float pl = 0.f;
    #pragma unroll
    for (int h = 0; h < 32; ++h) {
        int hg = half * 32 + h;                   // scalar
        float pre = fmaf(sinv, fmaf(-mu, c12[hg], acc[h]), c12[HDIM + hg]);
        float g   = 0.5f * pre * (1.f + erff(pre * 0.70710678118654752f));
        pl = fmaf(g, W2[hg], pl);
    }

    if (half) plog[tl] = pl;
    __syncthreads();
    if (!half) logits[t] = pl + plog[tl];
}

// ---------------- k_softmax: one block per b, in-place logits -> weights (softmax over N).
// b2 omitted: softmax is shift-invariant.
__global__ __launch_bounds__(256) void k_softmax(float* __restrict__ wts) {
    __shared__ float smax[4], ssum[4];
    int b = blockIdx.x;
    float* row = wts + (size_t)b * NTOK;
    int w = threadIdx.x >> 6, lane = threadIdx.x & 63;

    float v[4];
    float m = -1e30f;
    #pragma unroll
    for (int k = 0; k < 4; ++k) { v[k] = row[threadIdx.x + 256 * k]; m = fmaxf(m, v[k]); }
    #pragma unroll
    for (int off = 32; off; off >>= 1) m = fmaxf(m, __shfl_xor(m, off));
    if (lane == 0) smax[w] = m;
    __syncthreads();
    m = fmaxf(fmaxf(smax[0], smax[1]), fmaxf(smax[2], smax[3]));

    float s = 0.f;
    #pragma unroll
    for (int k = 0; k < 4; ++k) { v[k] = __expf(v[k] - m); s += v[k]; }
    #pragma unroll
    for (int off = 32; off; off >>= 1) s += __shfl_xor(s, off);
    if (lane == 0) ssum[w] = s;
    __syncthreads();
    s = (ssum[0] + ssum[1]) + (ssum[2] + ssum[3]);
    float inv = 1.f / s;
    #pragma unroll
    for (int k = 0; k < 4; ++k) row[threadIdx.x + 256 * k] = v[k] * inv;
}

// ---------------- k_partial: summary partials. blockIdx.x = n-split, blockIdx.y = b.
// thread = d (perfectly coalesced x reads), w[b][n] wave-uniform -> s_load.
__global__ __launch_bounds__(256) void k_partial(const float* __restrict__ x,
                                                 const float* __restrict__ wts,
                                                 float* __restrict__ part, int rows) {
    int b = blockIdx.y, s = blockIdx.x, d = threadIdx.x;
    int n0 = s * rows;
    const float* w  = wts + (size_t)b * NTOK + n0;
    const float* xp = x + ((size_t)b * NTOK + n0) * DDIM + d;

    float a0 = 0.f, a1 = 0.f, a2 = 0.f, a3 = 0.f, a4 = 0.f, a5 = 0.f, a6 = 0.f, a7 = 0.f;
    for (int n = 0; n < rows; n += 8) {
        a0 = fmaf(w[n + 0], xp[(size_t)(n + 0) * DDIM], a0);
        a1 = fmaf(w[n + 1], xp[(size_t)(n + 1) * DDIM], a1);
        a2 = fmaf(w[n + 2], xp[(size_t)(n + 2) * DDIM], a2);
        a3 = fmaf(w[n + 3], xp[(size_t)(n + 3) * DDIM], a3);
        a4 = fmaf(w[n + 4], xp[(size_t)(n + 4) * DDIM], a4);
        a5 = fmaf(w[n + 5], xp[(size_t)(n + 5) * DDIM], a5);
        a6 = fmaf(w[n + 6], xp[(size_t)(n + 6) * DDIM], a6);
        a7 = fmaf(w[n + 7], xp[(size_t)(n + 7) * DDIM], a7);
    }
    float acc = ((a0 + a1) + (a2 + a3)) + ((a4 + a5) + (a6 + a7));
    part[((size_t)(b * gridDim.x + s)) * DDIM + d] = acc;
}

// ---------------- k_reduce: summary[b,d] = sum_s part[b,s,d]
__global__ __launch_bounds__(256) void k_reduce(const float* __restrict__ part,
                                                float* __restrict__ out, int nsplit) {
    int i = blockIdx.x * 256 + threadIdx.x;   // i over B*D
    int b = i >> 8, d = i & 255;
    float s = 0.f;
    for (int k = 0; k < nsplit; ++k) s += part[((size_t)(b * nsplit + k)) * DDIM + d];
    out[i] = s;
}

extern "C" void kernel_launch(void* const* d_in, const int* in_sizes, int n_in,
                              void* d_out, int out_size, void* d_ws, size_t ws_size,
                              hipStream_t stream) {
    const float* x     = (const float*)d_in[0];
    const float* gamma = (const float*)d_in[1];
    const float* beta  = (const float*)d_in[2];
    const float* W1    = (const float*)d_in[3];
    const float* b1    = (const float*)d_in[4];
    const float* W2    = (const float*)d_in[5];
    // d_in[6] = b2: softmax-invariant, unused.

    float* out     = (float*)d_out;
    float* summary = out;                       // B*D
    float* wts     = out + (size_t)BDIM * DDIM; // B*N (logits staged here, then weights)

    float* c12  = (float*)d_ws;                 // 128 floats
    float* part = c12 + 128;                    // up to 8*B*D floats

    const int NSPLIT = 8;
    size_t need = (128 + (size_t)NSPLIT * BDIM * DDIM) * sizeof(float);
    bool split = (ws_size >= need);

    hipLaunchKernelGGL(k_pre, dim3(1), dim3(64), 0, stream, gamma, beta, W1, b1, c12);
    hipLaunchKernelGGL(k_logits, dim3(BDIM * NTOK / 128), dim3(256), 0, stream,
                       x, gamma, W1, W2, c12, wts);
    hipLaunchKernelGGL(k_softmax, dim3(BDIM), dim3(256), 0, stream, wts);
    if (split) {
        hipLaunchKernelGGL(k_partial, dim3(NSPLIT, BDIM), dim3(256), 0, stream,
                           x, wts, part, NTOK / NSPLIT);
        hipLaunchKernelGGL(k_reduce, dim3(BDIM * DDIM / 256), dim3(256), 0, stream,
                           part, summary, NSPLIT);
    } else {
        hipLaunchKernelGGL(k_partial, dim3(1, BDIM), dim3(256), 0, stream,
                           x, wts, summary, NTOK);
    }
}